// Round 9
// baseline (1178.711 us; speedup 1.0000x reference)
//
#include <hip/hip_runtime.h>
#include <hip/hip_bf16.h>

#define D_MODEL 128
#define SEQ_L   4096
#define BATCH   128
#define NSTRIP  4                    // strips per batch row
#define STRIP   (SEQ_L / NSTRIP)     // 1024 tokens per strip
#define NBLK    (BATCH * NSTRIP)     // 512 blocks = 2 per CU

typedef float f4 __attribute__((ext_vector_type(4)));
typedef float f32x4 __attribute__((ext_vector_type(4)));
typedef short bf16x8 __attribute__((ext_vector_type(8)));

__device__ __forceinline__ unsigned short f2bf(float f) {
    union { float f; unsigned u; } v; v.f = f;
    unsigned r = v.u + 0x7FFFu + ((v.u >> 16) & 1u);
    return (unsigned short)(r >> 16);
}

// device-scope grid barrier; ctr zeroed by hipMemsetAsync before every launch
__device__ __forceinline__ void gridbar(int* ctr, int idx) {
    __syncthreads();
    if (threadIdx.x == 0) {
        __threadfence();                       // release: prior stores visible agent-wide
        atomicAdd(&ctr[idx], 1);               // device-scope by default
        while (__hip_atomic_load(&ctr[idx], __ATOMIC_ACQUIRE, __HIP_MEMORY_SCOPE_AGENT) < NBLK)
            __builtin_amdgcn_s_sleep(1);
    }
    __syncthreads();
    __threadfence();                           // acquire side for all threads
}

template<bool GUARD>
__device__ __forceinline__ void load6(const float* __restrict__ xb, int gr0, int c4, f4 R[6]) {
    #pragma unroll
    for (int j = 0; j < 6; ++j) {
        int gr = gr0 + j;
        if (GUARD) {
            bool ok = (gr >= 0) && (gr < SEQ_L);
            int grc = ok ? gr : 0;
            f4 v = reinterpret_cast<const f4*>(xb + (size_t)grc * D_MODEL)[c4];
            f4 z = {0.f, 0.f, 0.f, 0.f};
            R[j] = ok ? v : z;
        } else {
            R[j] = reinterpret_cast<const f4*>(xb + (size_t)gr * D_MODEL)[c4];
        }
    }
}

__global__ __launch_bounds__(512, 4) void fused(const float* __restrict__ x,
                                                const float* __restrict__ W1,
                                                const float* __restrict__ b1,
                                                const float* __restrict__ W2,
                                                const float* __restrict__ b2,
                                                const float* __restrict__ Wc,
                                                const float* __restrict__ bc,
                                                float* __restrict__ out,
                                                int* __restrict__ ctr,
                                                float* __restrict__ part,
                                                float* __restrict__ wv,
                                                unsigned short* __restrict__ wcb) {
    __shared__ f4 red[512];
    __shared__ __align__(16) unsigned short y_lds[2][64][132];

    const int t = threadIdx.x, gid = blockIdx.x;
    const int b = gid >> 2, strip = gid & 3;
    const int sb = strip * STRIP;
    const float* xb = x + (size_t)b * SEQ_L * D_MODEL;
    float* outb = out + (size_t)b * SEQ_L * D_MODEL;

    // ================= phase 1: partial mean of own strip (+ Wc cvt on blocks 0..7) =================
    {
        int c4 = t & 31, ph = t >> 5;            // ph 0..15
        const f4* xv = reinterpret_cast<const f4*>(xb);
        f4 acc = {0.f, 0.f, 0.f, 0.f};
        for (int blk = 0; blk < 4; ++blk) {
            f4 R[16];
            #pragma unroll
            for (int j = 0; j < 16; ++j)
                R[j] = xv[(size_t)(sb + blk * 256 + ph + j * 16) * 32 + c4];
            #pragma unroll
            for (int s = 8; s >= 1; s >>= 1)
                #pragma unroll
                for (int j = 0; j < s; ++j) R[j] += R[j + s];
            acc += R[0];
        }
        if (gid < 8) {                            // Wc fp32 -> bf16 (4096 f4 chunks total)
            int i = gid * 512 + t;
            f4 v = reinterpret_cast<const f4*>(Wc)[i];
            ushort4 o;
            o.x = f2bf(v[0]); o.y = f2bf(v[1]); o.z = f2bf(v[2]); o.w = f2bf(v[3]);
            reinterpret_cast<ushort4*>(wcb)[i] = o;
        }
        red[t] = acc;
        __syncthreads();
        if (t < 32) {
            f4 s = red[t];
            #pragma unroll
            for (int p = 1; p < 16; ++p) s += red[t + 32 * p];
            reinterpret_cast<f4*>(part + ((size_t)b * NSTRIP + strip) * D_MODEL)[t] = s;
        }
    }
    gridbar(ctr, 0);

    // ================= phase 2: block 0 computes MLP+softmax -> wv[3][128] =================
    if (gid == 0 && t < 128) {
        int c = t;
        f4 mv[32];
        #pragma unroll
        for (int d4 = 0; d4 < 32; ++d4) mv[d4] = (f4){0.f, 0.f, 0.f, 0.f};
        for (int s = 0; s < NSTRIP; ++s) {
            const f4* ps = reinterpret_cast<const f4*>(part + ((size_t)c * NSTRIP + s) * D_MODEL);
            #pragma unroll
            for (int d4 = 0; d4 < 32; ++d4) mv[d4] += ps[d4];
        }
        #pragma unroll
        for (int d4 = 0; d4 < 32; ++d4) mv[d4] *= (1.0f / (float)SEQ_L);

        float h[32];
        #pragma unroll
        for (int j = 0; j < 32; ++j) {
            const f4* w1r = reinterpret_cast<const f4*>(W1 + j * 128);
            f4 s4 = {0.f, 0.f, 0.f, 0.f};
            #pragma unroll
            for (int d4 = 0; d4 < 32; ++d4) s4 += mv[d4] * w1r[d4];
            float s = s4[0] + s4[1] + s4[2] + s4[3] + b1[j];
            h[j] = 0.5f * s * (1.0f + erff(s * 0.70710678118654752f)); // exact gelu
        }
        float lg[3], mx = -1e30f;
        #pragma unroll
        for (int k = 0; k < 3; ++k) {
            float s = b2[k];
            #pragma unroll
            for (int j = 0; j < 32; ++j) s += h[j] * W2[k * 32 + j];
            lg[k] = s; mx = fmaxf(mx, s);
        }
        float e[3], den = 0.f;
        #pragma unroll
        for (int k = 0; k < 3; ++k) { e[k] = __expf(lg[k] - mx); den += e[k]; }
        float inv = 1.0f / den;
        #pragma unroll
        for (int k = 0; k < 3; ++k) wv[k * 128 + c] = e[k] * inv;
    }
    gridbar(ctr, 1);

    // ================= phase 3: conv + MFMA matmul on own strip (r6 proven loop) =================
    {
        int c4 = t & 31, rg = t >> 5;            // rg 0..15: rows rg*4..rg*4+3 of each half
        int lane = t & 63, wid = t >> 6;
        int r = lane & 15, q = lane >> 4, kb = q * 8;
        int co0 = wid * 16;

        f4 w0 = reinterpret_cast<const f4*>(wv)[c4];
        f4 w1 = reinterpret_cast<const f4*>(wv + 128)[c4];
        f4 w2 = reinterpret_cast<const f4*>(wv + 256)[c4];

        bf16x8 awc[4];
        #pragma unroll
        for (int kc = 0; kc < 4; ++kc)
            awc[kc] = *reinterpret_cast<const bf16x8*>(wcb + (size_t)(co0 + r) * D_MODEL + kc * 32 + kb);

        f4 bcv = *reinterpret_cast<const f4*>(bc + co0 + q * 4);

        f4 R[6];
        if (sb == 0) load6<true>(xb, sb + rg * 4 - 1, c4, R);
        else         load6<false>(xb, sb + rg * 4 - 1, c4, R);

        for (int h = 0; h < STRIP / 64; ++h) {
            const int buf = h & 1;
            int base = sb + h * 64;
            // conv (consumes R) + LDS write
            #pragma unroll
            for (int j = 0; j < 4; ++j) {
                f4 y = R[j] * w0 + R[j + 1] * w1 + R[j + 2] * w2;
                ushort4 yb;
                yb.x = f2bf(y[0]); yb.y = f2bf(y[1]); yb.z = f2bf(y[2]); yb.w = f2bf(y[3]);
                *reinterpret_cast<ushort4*>(&y_lds[buf][rg * 4 + j][c4 * 4]) = yb;
            }
            // issue next half's loads (fly under barrier+MFMA+stores)
            if (h < STRIP / 64 - 1) {
                int nb = base + 64;
                if (nb + 64 == SEQ_L) load6<true>(xb, nb + rg * 4 - 1, c4, R);
                else                  load6<false>(xb, nb + rg * 4 - 1, c4, R);
            }
            __syncthreads();   // y_lds[buf] visible

            f32x4 acc[4];
            #pragma unroll
            for (int g = 0; g < 4; ++g) acc[g] = (f32x4){0.f, 0.f, 0.f, 0.f};
            #pragma unroll
            for (int g = 0; g < 4; ++g)
                #pragma unroll
                for (int kc = 0; kc < 4; ++kc) {
                    bf16x8 bv = *reinterpret_cast<const bf16x8*>(&y_lds[buf][g * 16 + r][kc * 32 + kb]);
                    acc[g] = __builtin_amdgcn_mfma_f32_16x16x32_bf16(awc[kc], bv, acc[g], 0, 0, 0);
                }

            #pragma unroll
            for (int g = 0; g < 4; ++g) {
                int tok = base + g * 16 + r;
                *reinterpret_cast<f4*>(outb + (size_t)tok * D_MODEL + co0 + q * 4) = acc[g] + bcv;
            }
            __syncthreads();   // all waves done with y_lds[buf] before rewrite
        }
    }
}

extern "C" void kernel_launch(void* const* d_in, const int* in_sizes, int n_in,
                              void* d_out, int out_size, void* d_ws, size_t ws_size,
                              hipStream_t stream) {
    const float* x  = (const float*)d_in[0];
    const float* W1 = (const float*)d_in[1];
    const float* b1 = (const float*)d_in[2];
    const float* W2 = (const float*)d_in[3];
    const float* b2 = (const float*)d_in[4];
    const float* Wc = (const float*)d_in[5];
    const float* bc = (const float*)d_in[6];
    float* out = (float*)d_out;

    char* ws = (char*)d_ws;
    int* ctr = (int*)ws;                                      // 2 ints (zeroed below)
    float* part = (float*)(ws + 1024);                        // 128*4*128*4 = 256 KB
    float* wv   = (float*)(ws + 1024 + 262144);               // 1.5 KB
    unsigned short* wcb = (unsigned short*)(ws + 1024 + 262144 + 2048); // 32 KB

    hipMemsetAsync(ctr, 0, 128, stream);   // reset barrier counters every call (graph-legal)
    fused<<<NBLK, 512, 0, stream>>>(x, W1, b1, W2, b2, Wc, bc, out, ctr, part, wv, wcb);
}

// Round 11
// 271.640 us; speedup vs baseline: 4.3392x; 4.3392x over previous
//
#include <hip/hip_runtime.h>
#include <hip/hip_bf16.h>

#define D_MODEL 128
#define SEQ_L   4096
#define BATCH   128
#define NSTRIP  2                    // strips per batch row
#define STRIP   (SEQ_L / NSTRIP)     // 2048 tokens per strip
#define NBLK    (BATCH * NSTRIP)     // 256 blocks = deadlock-safe at ANY occupancy >= 1/CU

typedef float f4 __attribute__((ext_vector_type(4)));
typedef float f32x4 __attribute__((ext_vector_type(4)));
typedef short bf16x8 __attribute__((ext_vector_type(8)));

__device__ __forceinline__ unsigned short f2bf(float f) {
    union { float f; unsigned u; } v; v.f = f;
    unsigned r = v.u + 0x7FFFu + ((v.u >> 16) & 1u);
    return (unsigned short)(r >> 16);
}

// device-scope grid barrier; ctr zeroed by hipMemsetAsync before every launch
__device__ __forceinline__ void gridbar(int* ctr) {
    __syncthreads();
    if (threadIdx.x == 0) {
        __threadfence();                       // release
        atomicAdd(ctr, 1);
        while (__hip_atomic_load(ctr, __ATOMIC_ACQUIRE, __HIP_MEMORY_SCOPE_AGENT) < NBLK)
            __builtin_amdgcn_s_sleep(1);
    }
    __syncthreads();
    __threadfence();                           // acquire side for all threads
}

template<bool GUARD>
__device__ __forceinline__ void load6(const float* __restrict__ xb, int gr0, int c4, f4 R[6]) {
    #pragma unroll
    for (int j = 0; j < 6; ++j) {
        int gr = gr0 + j;
        if (GUARD) {
            bool ok = (gr >= 0) && (gr < SEQ_L);
            int grc = ok ? gr : 0;
            f4 v = reinterpret_cast<const f4*>(xb + (size_t)grc * D_MODEL)[c4];
            f4 z = {0.f, 0.f, 0.f, 0.f};
            R[j] = ok ? v : z;
        } else {
            R[j] = reinterpret_cast<const f4*>(xb + (size_t)gr * D_MODEL)[c4];
        }
    }
}

__global__ __launch_bounds__(512, 2) void fused(const float* __restrict__ x,
                                                const float* __restrict__ W1,
                                                const float* __restrict__ b1,
                                                const float* __restrict__ W2,
                                                const float* __restrict__ b2,
                                                const float* __restrict__ Wc,
                                                const float* __restrict__ bc,
                                                float* __restrict__ out,
                                                int* __restrict__ ctr,
                                                float* __restrict__ part) {
    __shared__ f4 red[512];
    __shared__ __align__(16) unsigned short y_lds[2][64][132];
    __shared__ __align__(16) float wv_lds[3][128];

    const int t = threadIdx.x, gid = blockIdx.x;
    const int b = gid >> 1, strip = gid & 1;
    const int sb = strip * STRIP;
    const float* xb = x + (size_t)b * SEQ_L * D_MODEL;
    float* outb = out + (size_t)b * SEQ_L * D_MODEL;

    // ============ phase 1: partial mean of own 2048-token strip ============
    {
        int c4 = t & 31, ph = t >> 5;            // ph 0..15
        const f4* xv = reinterpret_cast<const f4*>(xb);
        f4 acc = {0.f, 0.f, 0.f, 0.f};
        for (int o = 0; o < STRIP / 128; ++o) {  // 16 x 128 tokens
            f4 R[8];
            #pragma unroll
            for (int j = 0; j < 8; ++j)
                R[j] = xv[(size_t)(sb + o * 128 + ph + j * 16) * 32 + c4];
            R[0] += R[4]; R[1] += R[5]; R[2] += R[6]; R[3] += R[7];
            R[0] += R[2]; R[1] += R[3];
            acc += R[0] + R[1];
        }
        red[t] = acc;
        __syncthreads();
        if (t < 32) {
            f4 s = red[t];
            #pragma unroll
            for (int p = 1; p < 16; ++p) s += red[t + 32 * p];
            reinterpret_cast<f4*>(part + ((size_t)b * NSTRIP + strip) * D_MODEL)[t] = s;
        }
    }
    gridbar(ctr);   // part complete, visible device-wide

    // ============ phase 2: EVERY block redundantly computes wv[3][128] -> LDS ============
    // channel c handled by 4 partner threads (t = c*4+p), each owns 32 of the 128 dims.
    {
        int c = t >> 2, p = t & 3;
        f4 mv[8];
        #pragma unroll
        for (int d4 = 0; d4 < 8; ++d4) mv[d4] = (f4){0.f, 0.f, 0.f, 0.f};
        #pragma unroll
        for (int s = 0; s < NSTRIP; ++s) {
            const f4* ps = reinterpret_cast<const f4*>(part + ((size_t)c * NSTRIP + s) * D_MODEL + p * 32);
            #pragma unroll
            for (int d4 = 0; d4 < 8; ++d4) mv[d4] += ps[d4];
        }
        #pragma unroll
        for (int d4 = 0; d4 < 8; ++d4) mv[d4] *= (1.0f / (float)SEQ_L);

        float h[32];
        #pragma unroll
        for (int j = 0; j < 32; ++j) {
            const f4* w1r = reinterpret_cast<const f4*>(W1 + j * 128 + p * 32);
            f4 s4 = {0.f, 0.f, 0.f, 0.f};
            #pragma unroll
            for (int d4 = 0; d4 < 8; ++d4) s4 += mv[d4] * w1r[d4];
            float s = s4[0] + s4[1] + s4[2] + s4[3];
            s += __shfl_xor(s, 1);
            s += __shfl_xor(s, 2);               // full 128-dot on all 4 partners
            s += b1[j];
            h[j] = 0.5f * s * (1.0f + erff(s * 0.70710678118654752f)); // exact gelu
        }
        if (p == 0) {
            float lg[3], mx = -1e30f;
            #pragma unroll
            for (int k = 0; k < 3; ++k) {
                float s = b2[k];
                #pragma unroll
                for (int j = 0; j < 32; ++j) s += h[j] * W2[k * 32 + j];
                lg[k] = s; mx = fmaxf(mx, s);
            }
            float e[3], den = 0.f;
            #pragma unroll
            for (int k = 0; k < 3; ++k) { e[k] = __expf(lg[k] - mx); den += e[k]; }
            float inv = 1.0f / den;
            #pragma unroll
            for (int k = 0; k < 3; ++k) wv_lds[k][c] = e[k] * inv;
        }
    }
    __syncthreads();   // wv_lds ready (block-local)

    // ============ phase 3: conv + MFMA matmul on own strip (r6 proven loop) ============
    {
        int c4 = t & 31, rg = t >> 5;            // rg 0..15: rows rg*4..rg*4+3 of each half
        int lane = t & 63, wid = t >> 6;
        int r = lane & 15, q = lane >> 4, kb = q * 8;
        int co0 = wid * 16;

        f4 w0 = *reinterpret_cast<const f4*>(&wv_lds[0][c4 * 4]);
        f4 w1 = *reinterpret_cast<const f4*>(&wv_lds[1][c4 * 4]);
        f4 w2 = *reinterpret_cast<const f4*>(&wv_lds[2][c4 * 4]);

        // Wc A-fragments straight from fp32 (L2/L3-hot), cvt in registers
        bf16x8 awc[4];
        #pragma unroll
        for (int kc = 0; kc < 4; ++kc) {
            const float* wr = Wc + (size_t)(co0 + r) * D_MODEL + kc * 32 + kb;
            f4 a = *reinterpret_cast<const f4*>(wr);
            f4 bb = *reinterpret_cast<const f4*>(wr + 4);
            bf16x8 fr;
            fr[0] = (short)f2bf(a[0]); fr[1] = (short)f2bf(a[1]);
            fr[2] = (short)f2bf(a[2]); fr[3] = (short)f2bf(a[3]);
            fr[4] = (short)f2bf(bb[0]); fr[5] = (short)f2bf(bb[1]);
            fr[6] = (short)f2bf(bb[2]); fr[7] = (short)f2bf(bb[3]);
            awc[kc] = fr;
        }

        f4 bcv = *reinterpret_cast<const f4*>(bc + co0 + q * 4);

        f4 R[6];
        if (sb == 0) load6<true>(xb, sb + rg * 4 - 1, c4, R);
        else         load6<false>(xb, sb + rg * 4 - 1, c4, R);

        for (int ht = 0; ht < STRIP / 64; ++ht) {
            const int buf = ht & 1;
            int base = sb + ht * 64;
            // conv (consumes R) + LDS write
            #pragma unroll
            for (int j = 0; j < 4; ++j) {
                f4 y = R[j] * w0 + R[j + 1] * w1 + R[j + 2] * w2;
                ushort4 yb;
                yb.x = f2bf(y[0]); yb.y = f2bf(y[1]); yb.z = f2bf(y[2]); yb.w = f2bf(y[3]);
                *reinterpret_cast<ushort4*>(&y_lds[buf][rg * 4 + j][c4 * 4]) = yb;
            }
            // issue next half's loads (fly under barrier+MFMA+stores)
            if (ht < STRIP / 64 - 1) {
                int nb = base + 64;
                if (nb + 64 == SEQ_L) load6<true>(xb, nb + rg * 4 - 1, c4, R);
                else                  load6<false>(xb, nb + rg * 4 - 1, c4, R);
            }
            __syncthreads();   // y_lds[buf] visible

            f32x4 acc[4];
            #pragma unroll
            for (int g = 0; g < 4; ++g) acc[g] = (f32x4){0.f, 0.f, 0.f, 0.f};
            #pragma unroll
            for (int g = 0; g < 4; ++g)
                #pragma unroll
                for (int kc = 0; kc < 4; ++kc) {
                    bf16x8 bv = *reinterpret_cast<const bf16x8*>(&y_lds[buf][g * 16 + r][kc * 32 + kb]);
                    acc[g] = __builtin_amdgcn_mfma_f32_16x16x32_bf16(awc[kc], bv, acc[g], 0, 0, 0);
                }

            #pragma unroll
            for (int g = 0; g < 4; ++g) {
                int tok = base + g * 16 + r;
                *reinterpret_cast<f4*>(outb + (size_t)tok * D_MODEL + co0 + q * 4) = acc[g] + bcv;
            }
            __syncthreads();   // all waves done with y_lds[buf] before rewrite
        }
    }
}

extern "C" void kernel_launch(void* const* d_in, const int* in_sizes, int n_in,
                              void* d_out, int out_size, void* d_ws, size_t ws_size,
                              hipStream_t stream) {
    const float* x  = (const float*)d_in[0];
    const float* W1 = (const float*)d_in[1];
    const float* b1 = (const float*)d_in[2];
    const float* W2 = (const float*)d_in[3];
    const float* b2 = (const float*)d_in[4];
    const float* Wc = (const float*)d_in[5];
    const float* bc = (const float*)d_in[6];
    float* out = (float*)d_out;

    char* ws = (char*)d_ws;
    int* ctr = (int*)ws;                                      // barrier counter (zeroed below)
    float* part = (float*)(ws + 1024);                        // 128*2*128*4 = 128 KB

    hipMemsetAsync(ctr, 0, 128, stream);   // reset barrier counter every call (graph-legal)
    fused<<<NBLK, 512, 0, stream>>>(x, W1, b1, W2, b2, Wc, bc, out, ctr, part);
}